// Round 18
// baseline (240.204 us; speedup 1.0000x reference)
//
#include <hip/hip_runtime.h>
#include <stdint.h>

#define NB     4
#define SEQ    2048
#define NH     16
#define DHD    64
#define DM     1024
#define MTOT   (NB*SEQ)     // 8192
#define HSZ    (SEQ*DHD)    // 131072 shorts per (b,h) in K'/V'

typedef __attribute__((ext_vector_type(8))) short bf16x8;
typedef __attribute__((ext_vector_type(4))) float f32x4;

__device__ __forceinline__ short f2bf(float f) {
  uint32_t u = __float_as_uint(f);
  u = (u + 0x7FFFu + ((u >> 16) & 1u)) >> 16;   // RNE, finite inputs only
  return (short)u;
}

__device__ __forceinline__ uint32_t cvtpk(float lo, float hi) {
  uint32_t r;
  asm("v_cvt_pk_bf16_f32 %0, %1, %2" : "=v"(r) : "v"(lo), "v"(hi));
  return r;
}

__device__ __forceinline__ float exp2a(float x) {   // v_exp_f32 = 2^x
  float r;
  asm("v_exp_f32 %0, %1" : "=v"(r) : "v"(x));
  return r;
}

__device__ __forceinline__ float max3f(float a, float b, float c) {
  return fmaxf(fmaxf(a, b), c);                     // clang fuses to v_max3_f32
}

__device__ __forceinline__ f32x4 mfma16(bf16x8 a, bf16x8 b, f32x4 c) {
  return __builtin_amdgcn_mfma_f32_16x16x32_bf16(a, b, c, 0, 0, 0);
}

__device__ __forceinline__ void async16(const void* g, void* l) {
  __builtin_amdgcn_global_load_lds(
      (const __attribute__((address_space(1))) void*)g,
      (__attribute__((address_space(3))) void*)l, 16, 0, 0);
}

// ---- cast x f32 -> bf16 ----
__global__ void k_cast(const float* __restrict__ in, short* __restrict__ out, int n) {
  int i = (blockIdx.x * blockDim.x + threadIdx.x) * 8;
  if (i >= n) return;
  float4 a = *reinterpret_cast<const float4*>(in + i);
  float4 b = *reinterpret_cast<const float4*>(in + i + 4);
  bf16x8 v;
  v[0] = f2bf(a.x); v[1] = f2bf(a.y); v[2] = f2bf(a.z); v[3] = f2bf(a.w);
  v[4] = f2bf(b.x); v[5] = f2bf(b.y); v[6] = f2bf(b.z); v[7] = f2bf(b.w);
  *reinterpret_cast<bf16x8*>(out + i) = v;
}

// ---- mask -> additive float bias ----
__global__ void k_maskbias(const int* __restrict__ pm, float* __restrict__ fb, int n) {
  int i = blockIdx.x * blockDim.x + threadIdx.x;
  if (i < n) fb[i] = pm[i] ? 0.0f : -1e30f;
}

// ---- transpose+cast 4 weights in one launch (grid.z selects matrix) ----
__global__ void k_transpose4(const float* __restrict__ Wq, const float* __restrict__ Wk,
                             const float* __restrict__ Wv, const float* __restrict__ Wo,
                             short* __restrict__ wqkv, short* __restrict__ wot) {
  __shared__ float tile[32][33];
  int z = blockIdx.z;
  const float* in = (z == 0) ? Wq : (z == 1) ? Wk : (z == 2) ? Wv : Wo;
  short* out = (z < 3) ? (wqkv + (size_t)z * 1024 * DM) : wot;
  int n0 = blockIdx.x * 32, k0 = blockIdx.y * 32;
  int tx = threadIdx.x, ty = threadIdx.y;   // block (32,8)
  #pragma unroll
  for (int i = 0; i < 32; i += 8)
    tile[ty + i][tx] = in[(size_t)(k0 + ty + i) * DM + n0 + tx];
  __syncthreads();
  #pragma unroll
  for (int i = 0; i < 32; i += 8)
    out[(size_t)(n0 + ty + i) * DM + k0 + tx] = f2bf(tile[tx][ty + i]);
}

// ---- fused QKV GEMM: 8192 x 3072 x 1024, Bt = packed [3072][1024] ----
__global__ void __launch_bounds__(256) k_gemm_qkv(const short* __restrict__ A,
                                                  const short* __restrict__ Bt,
                                                  const float* __restrict__ bq,
                                                  const float* __restrict__ bk,
                                                  const float* __restrict__ bv,
                                                  short* __restrict__ Qo,
                                                  short* __restrict__ KF,
                                                  short* __restrict__ VF,
                                                  float qscale) {
  __shared__ short lA[128 * 32];
  __shared__ short lB[128 * 32];
  int lin = blockIdx.y * gridDim.x + blockIdx.x;      // 1536 blocks, %8==0
  int swz = (lin & 7) * 192 + (lin >> 3);             // bijective XCD swizzle
  int m0 = (swz & 63) * 128, n0 = (swz >> 6) * 128;   // n0 in [0,3072)
  int seg = n0 >> 10;                                 // 0=Q 1=K 2=V (block-uniform)
  const float* bias = (seg == 0) ? bq : (seg == 1) ? bk : bv;
  float scale = (seg == 0) ? qscale : 1.0f;
  int tid = threadIdx.x, lane = tid & 63, w = tid >> 6;
  int wr = w >> 1, wc = w & 1;
  int l15 = lane & 15, lg = lane >> 4;
  f32x4 acc[4][4] = {};

  int r0 = tid >> 2, c0 = (tid & 3) * 8;
  int r1 = (tid + 256) >> 2, c1 = ((tid + 256) & 3) * 8;
  const short* ga0 = A + (size_t)(m0 + r0) * DM + c0;
  const short* ga1 = A + (size_t)(m0 + r1) * DM + c1;
  const short* gb0 = Bt + (size_t)(n0 + r0) * DM + c0;
  const short* gb1 = Bt + (size_t)(n0 + r1) * DM + c1;
  short* lA0 = lA + w * 512;
  short* lA1 = lA + 2048 + w * 512;
  short* lB0 = lB + w * 512;
  short* lB1 = lB + 2048 + w * 512;

  for (int k0 = 0; k0 < DM; k0 += 32) {
    async16(ga0 + k0, lA0);
    async16(ga1 + k0, lA1);
    async16(gb0 + k0, lB0);
    async16(gb1 + k0, lB1);
    __syncthreads();
    bf16x8 af[4], bfr[4];
    #pragma unroll
    for (int i = 0; i < 4; ++i) {
      af[i]  = *reinterpret_cast<const bf16x8*>(lA + (wr * 64 + i * 16 + l15) * 32 + lg * 8);
      bfr[i] = *reinterpret_cast<const bf16x8*>(lB + (wc * 64 + i * 16 + l15) * 32 + lg * 8);
    }
    #pragma unroll
    for (int i = 0; i < 4; ++i)
      #pragma unroll
      for (int j = 0; j < 4; ++j)
        acc[i][j] = mfma16(af[i], bfr[j], acc[i][j]);
    __syncthreads();
  }

  #pragma unroll
  for (int j = 0; j < 4; ++j) {
    int cg = n0 + wc * 64 + j * 16 + l15;
    int cloc = cg & 1023;
    float bval = bias[cloc];
    #pragma unroll
    for (int i = 0; i < 4; ++i) {
      #pragma unroll
      for (int r = 0; r < 4; ++r) {
        int rg = m0 + wr * 64 + i * 16 + lg * 4 + r;
        float val = (acc[i][j][r] + bval) * scale;
        if (seg == 0) {
          Qo[(size_t)rg * DM + cloc] = f2bf(val);
        } else if (seg == 1) {
          int bh2 = ((rg >> 11) << 4) | (cloc >> 6);
          int dh = cloc & 63, sl = rg & 2047;
          size_t fi = (size_t)bh2 * HSZ + (size_t)(sl >> 4) * 1024
                    + (size_t)((((dh >> 3) * 16 + (sl & 15)) * 8) + (dh & 7));
          KF[fi] = f2bf(val);
        } else {
          int bh2 = ((rg >> 11) << 4) | (cloc >> 6);
          int dh = cloc & 63, sl = rg & 2047;
          size_t fi = (size_t)bh2 * HSZ + (size_t)(sl >> 6) * 4096
                    + (size_t)((((dh >> 4) * 8 + ((sl >> 3) & 7)) * 16 + (dh & 15)) * 8 + (sl & 7));
          VF[fi] = f2bf(val);
        }
      }
    }
  }
}

// ---- final GEMM: ob @ Wo^T -> f32 out ----
__global__ void __launch_bounds__(256) k_gemm_out(const short* __restrict__ A,
                                                  const short* __restrict__ Bt,
                                                  const float* __restrict__ bias,
                                                  float* __restrict__ C) {
  __shared__ short lA[128 * 32];
  __shared__ short lB[128 * 32];
  int lin = blockIdx.y * gridDim.x + blockIdx.x;      // 512 blocks, %8==0
  int s = ((lin & 7) << 6) | (lin >> 3);              // bijective XCD swizzle
  int m0 = (s & 63) * 128, n0 = (s >> 6) * 128;
  int tid = threadIdx.x, lane = tid & 63, w = tid >> 6;
  int wr = w >> 1, wc = w & 1;
  int l15 = lane & 15, lg = lane >> 4;
  f32x4 acc[4][4] = {};

  int r0 = tid >> 2, c0 = (tid & 3) * 8;
  int r1 = (tid + 256) >> 2, c1 = ((tid + 256) & 3) * 8;
  const short* ga0 = A + (size_t)(m0 + r0) * DM + c0;
  const short* ga1 = A + (size_t)(m0 + r1) * DM + c1;
  const short* gb0 = Bt + (size_t)(n0 + r0) * DM + c0;
  const short* gb1 = Bt + (size_t)(n0 + r1) * DM + c1;
  short* lA0 = lA + w * 512;
  short* lA1 = lA + 2048 + w * 512;
  short* lB0 = lB + w * 512;
  short* lB1 = lB + 2048 + w * 512;

  for (int k0 = 0; k0 < DM; k0 += 32) {
    async16(ga0 + k0, lA0);
    async16(ga1 + k0, lA1);
    async16(gb0 + k0, lB0);
    async16(gb1 + k0, lB1);
    __syncthreads();
    bf16x8 af[4], bfr[4];
    #pragma unroll
    for (int i = 0; i < 4; ++i) {
      af[i]  = *reinterpret_cast<const bf16x8*>(lA + (wr * 64 + i * 16 + l15) * 32 + lg * 8);
      bfr[i] = *reinterpret_cast<const bf16x8*>(lB + (wc * 64 + i * 16 + l15) * 32 + lg * 8);
    }
    #pragma unroll
    for (int i = 0; i < 4; ++i)
      #pragma unroll
      for (int j = 0; j < 4; ++j)
        acc[i][j] = mfma16(af[i], bfr[j], acc[i][j]);
    __syncthreads();
  }

  #pragma unroll
  for (int j = 0; j < 4; ++j) {
    int cg = n0 + wc * 64 + j * 16 + l15;
    float bv = bias[cg];
    #pragma unroll
    for (int i = 0; i < 4; ++i) {
      #pragma unroll
      for (int r = 0; r < 4; ++r) {
        int rg = m0 + wr * 64 + i * 16 + lg * 4 + r;
        C[(size_t)rg * DM + cg] = acc[i][j][r] + bv;
      }
    }
  }
}

// issue the 8 K'-fragment loads for tile kt into DST (software pipeline)
#define ISSUE_KA(DST, KT) do {                                              \
  const short* kp_ = kbase + (size_t)((KT) >> 4) * 1024;                    \
  _Pragma("unroll")                                                         \
  for (int t_ = 0; t_ < 4; ++t_) {                                          \
    DST[t_][0] = *reinterpret_cast<const bf16x8*>(kp_ + t_ * 1024);         \
    DST[t_][1] = *reinterpret_cast<const bf16x8*>(kp_ + t_ * 1024 + 512);   \
  }                                                                         \
} while (0)

// logits + lane-local max (no cross-lane)
#define LOGITS(ST, FB4, D0, L, TMX) do {                                    \
  _Pragma("unroll")                                                         \
  for (int t_ = 0; t_ < 4; ++t_) {                                          \
    L[t_ * 4 + 0] = fmaf(-c2, fabsf((D0) - (float)(t_ * 16 + 0)), ST[t_][0] + FB4[t_].x); \
    L[t_ * 4 + 1] = fmaf(-c2, fabsf((D0) - (float)(t_ * 16 + 1)), ST[t_][1] + FB4[t_].y); \
    L[t_ * 4 + 2] = fmaf(-c2, fabsf((D0) - (float)(t_ * 16 + 2)), ST[t_][2] + FB4[t_].z); \
    L[t_ * 4 + 3] = fmaf(-c2, fabsf((D0) - (float)(t_ * 16 + 3)), ST[t_][3] + FB4[t_].w); \
  }                                                                         \
  float ma_ = max3f(L[0], L[1], L[2]);                                      \
  float mb_ = max3f(L[3], L[4], L[5]);                                      \
  float mc_ = max3f(L[6], L[7], L[8]);                                      \
  float md_ = max3f(L[9], L[10], L[11]);                                    \
  float me_ = max3f(L[12], L[13], L[14]);                                   \
  TMX = fmaxf(max3f(ma_, mb_, mc_), max3f(md_, me_, L[15]));                \
} while (0)

// rare full reduce + rescale (defer-max safety net; never fires on this data)
#define RESCALE(TMX, MRUN, SSUM, ACC) do {                                  \
  TMX = fmaxf(TMX, __shfl_xor(TMX, 16));                                    \
  TMX = fmaxf(TMX, __shfl_xor(TMX, 32));                                    \
  float mn_ = fmaxf(MRUN, TMX);                                             \
  float fsc_ = exp2a(MRUN - mn_);                                           \
  MRUN = mn_; SSUM *= fsc_;                                                 \
  _Pragma("unroll")                                                         \
  for (int td_ = 0; td_ < 4; ++td_) ACC[td_] *= fsc_;                       \
} while (0)

// exp + per-lane partial sum + strip write (fire-and-forget)
#define FINISH(L, MRUN, SSUM, WB) do {                                      \
  float p_[16];                                                             \
  _Pragma("unroll")                                                         \
  for (int i_ = 0; i_ < 16; ++i_) p_[i_] = exp2a(L[i_] - MRUN);             \
  float a0_ = p_[0] + p_[1],  a1_ = p_[2] + p_[3];                          \
  float a2_ = p_[4] + p_[5],  a3_ = p_[6] + p_[7];                          \
  float a4_ = p_[8] + p_[9],  a5_ = p_[10] + p_[11];                        \
  float a6_ = p_[12] + p_[13], a7_ = p_[14] + p_[15];                       \
  SSUM += ((a0_ + a1_) + (a2_ + a3_)) + ((a4_ + a5_) + (a6_ + a7_));        \
  _Pragma("unroll")                                                         \
  for (int t_ = 0; t_ < 4; ++t_) {                                          \
    uint2 wv_ = { cvtpk(p_[t_ * 4 + 0], p_[t_ * 4 + 1]),                    \
                  cvtpk(p_[t_ * 4 + 2], p_[t_ * 4 + 3]) };                  \
    *reinterpret_cast<uint2*>((WB) + t_ * 8 + lg * 2) = wv_;                \
  }                                                                         \
} while (0)

// PV for one half from a PREVIOUS tile's strip (data long landed; compiler
// inserts the lgkmcnt for the ds_read results -- no manual waits)
#define PVHALF(ACC, WBP, VAP) do {                                          \
  _Pragma("unroll")                                                         \
  for (int ks_ = 0; ks_ < 2; ++ks_) {                                       \
    int t_ = ks_ * 2 + (lg >> 1);                                           \
    bf16x8 pf_ = *reinterpret_cast<const bf16x8*>((WBP) + t_ * 8 + (lg & 1) * 4); \
    _Pragma("unroll")                                                       \
    for (int td_ = 0; td_ < 4; ++td_)                                       \
      ACC[td_] = mfma16(VAP[td_][ks_], pf_, ACC[td_]);                      \
  }                                                                         \
} while (0)

// one 64-KV tile: QK^T + softmax + strip-write for tile KT; PV for tile KT-64
// (pipelined one tile behind -> strip LDS round-trip off the critical path)
#define TILE(KA, KAN, VA, VAP, WBA, WBB, WBAP, WBBP, KT, PRE, PREV) do {    \
  float4 fb4[4];                                                            \
  _Pragma("unroll")                                                         \
  for (int t_ = 0; t_ < 4; ++t_)                                            \
    fb4[t_] = *reinterpret_cast<const float4*>(fb + (KT) + t_ * 16 + lg * 4);\
  const short* vp_ = vbase + (size_t)((KT) >> 6) * 4096;                    \
  _Pragma("unroll")                                                         \
  for (int td_ = 0; td_ < 4; ++td_) {                                       \
    VA[td_][0] = *reinterpret_cast<const bf16x8*>(vp_ + (td_ * 8 + 0) * 128);\
    VA[td_][1] = *reinterpret_cast<const bf16x8*>(vp_ + (td_ * 8 + 4) * 128);\
  }                                                                         \
  if (PRE) { ISSUE_KA(KAN, (KT) + 64); }                                    \
  __builtin_amdgcn_sched_barrier(0);                                        \
  f32x4 stA[4], stB[4];                                                     \
  __builtin_amdgcn_s_setprio(1);                                            \
  _Pragma("unroll")                                                         \
  for (int t_ = 0; t_ < 4; ++t_) {                                          \
    f32x4 zA = {};                                                          \
    zA = mfma16(KA[t_][0], bqA0, zA);                                       \
    stA[t_] = mfma16(KA[t_][1], bqA1, zA);                                  \
    f32x4 zB = {};                                                          \
    zB = mfma16(KA[t_][0], bqB0, zB);                                       \
    stB[t_] = mfma16(KA[t_][1], bqB1, zB);                                  \
  }                                                                         \
  __builtin_amdgcn_s_setprio(0);                                            \
  float lA_[16], lB_[16], tmA_, tmB_;                                       \
  LOGITS(stA, fb4, d0A, lA_, tmA_);                                         \
  LOGITS(stB, fb4, d0B, lB_, tmB_);                                         \
  bool pvA_ = false, pvB_ = false;                                          \
  if (!__all(tmA_ <= mrunA + 8.0f)) {                                       \
    if (PREV) { PVHALF(accA, WBAP, VAP); pvA_ = true; }                     \
    RESCALE(tmA_, mrunA, ssumA, accA);                                      \
  }                                                                         \
  if (!__all(tmB_ <= mrunB + 8.0f)) {                                       \
    if (PREV) { PVHALF(accB, WBBP, VAP); pvB_ = true; }                     \
    RESCALE(tmB_, mrunB, ssumB, accB);                                      \
  }                                                                         \
  FINISH(lA_, mrunA, ssumA, WBA);                                           \
  FINISH(lB_, mrunB, ssumB, WBB);                                           \
  __builtin_amdgcn_s_setprio(1);                                            \
  if ((PREV) && !pvA_) PVHALF(accA, WBAP, VAP);                             \
  if ((PREV) && !pvB_) PVHALF(accB, WBBP, VAP);                             \
  __builtin_amdgcn_s_setprio(0);                                            \
  d0A -= 64.0f; d0B -= 64.0f;                                               \
} while (0)

// ---- flash attention: 1 wave/block, fragment-direct K'/V', ka prefetch,
// shuffle-free softmax, PV lagged one tile (double-buffered strips + va).
// __launch_bounds__(64, 2): true block size declared, cap 256 (session rule).
__global__ void __launch_bounds__(64, 2) k_attn(const short* __restrict__ Q,
                                                const short* __restrict__ KF,
                                                const short* __restrict__ VF,
                                                const float* __restrict__ fbias,
                                                short* __restrict__ O) {
  __shared__ uint32_t pbuf[4 * 16 * 38];     // 9.7 KB: 2 strip sets x 2 halves
  // unmap: XCD = g&7 = bh&7; qb = (g>>3)&63; bh = (g&7) + 8*(g>>9)
  int g = blockIdx.x;
  int qb = (g >> 3) & 63;
  int bh = (g & 7) + ((g >> 9) << 3);
  int b = bh >> 4, h = bh & 15;
  int lane = threadIdx.x;
  int l15 = lane & 15, lg = lane >> 4;
  int q0 = qb * 32;
  // log2 domain: c2 = slope/sqrt(64) * log2e
  float c2 = exp2f(-0.5f * (float)(h + 1)) * 0.125f * 1.44269504f;

  // Q as B-fragments; Q pre-scaled by log2e/8 in GEMM epilogue
  const short* qpA = Q + (size_t)(b * SEQ + q0 + l15) * DM + h * DHD + lg * 8;
  bf16x8 bqA0 = *reinterpret_cast<const bf16x8*>(qpA);
  bf16x8 bqA1 = *reinterpret_cast<const bf16x8*>(qpA + 32);
  const short* qpB = qpA + (size_t)16 * DM;
  bf16x8 bqB0 = *reinterpret_cast<const bf16x8*>(qpB);
  bf16x8 bqB1 = *reinterpret_cast<const bf16x8*>(qpB + 32);

  const short* kbase = KF + (size_t)bh * HSZ + lane * 8;
  const short* vbase = VF + (size_t)bh * HSZ + lane * 8;
  const float* fb = fbias + b * SEQ;
  uint32_t* wbA0 = pbuf + l15 * 38;
  uint32_t* wbB0 = pbuf + 608 + l15 * 38;
  uint32_t* wbA1 = pbuf + 1216 + l15 * 38;
  uint32_t* wbB1 = pbuf + 1824 + l15 * 38;

  // mrun init 0 (not -inf): logits O(5); defer-max safety net handles spikes
  float mrunA = 0.0f, ssumA = 0.0f, mrunB = 0.0f, ssumB = 0.0f;
  f32x4 accA[4] = {}, accB[4] = {};
  float d0A = (float)(q0 + l15) - (float)(lg * 4);
  float d0B = d0A + 16.0f;

  bf16x8 kaX[4][2], kaY[4][2], vaX[4][2], vaY[4][2];
  ISSUE_KA(kaX, 0);                          // prologue

  // tile 0 (no pending PV), tile 1 (PV of tile 0), then 15 pairs
  TILE(kaX, kaY, vaX, vaY, wbA0, wbB0, wbA1, wbB1, 0, true, false);
  TILE(kaY, kaX, vaY, vaX, wbA1, wbB1, wbA0, wbB0, 64, true, true);
  for (int kt = 128; kt < SEQ; kt += 128) {
    TILE(kaX, kaY, vaX, vaY, wbA0, wbB0, wbA1, wbB1, kt, true, true);
    TILE(kaY, kaX, vaY, vaX, wbA1, wbB1, wbA0, wbB0, kt + 64, (kt + 128) < SEQ, true);
  }
  // drain final pending PV (last tile wrote strips1 with va in vaY)
  __builtin_amdgcn_s_setprio(1);
  PVHALF(accA, wbA1, vaY);
  PVHALF(accB, wbB1, vaY);
  __builtin_amdgcn_s_setprio(0);

  // combine per-lane ssum partials ONCE
  ssumA += __shfl_xor(ssumA, 16);
  ssumA += __shfl_xor(ssumA, 32);
  ssumB += __shfl_xor(ssumB, 16);
  ssumB += __shfl_xor(ssumB, 32);

  float invA = 1.0f / ssumA;
  float invB = 1.0f / ssumB;
  short* opA = O + (size_t)(b * SEQ + q0 + l15) * DM + h * DHD;
  short* opB = opA + (size_t)16 * DM;
  #pragma unroll
  for (int td = 0; td < 4; ++td) {
    uint2 wvA = { cvtpk(accA[td][0] * invA, accA[td][1] * invA),
                  cvtpk(accA[td][2] * invA, accA[td][3] * invA) };
    *reinterpret_cast<uint2*>(opA + td * 16 + lg * 4) = wvA;
    uint2 wvB = { cvtpk(accB[td][0] * invB, accB[td][1] * invB),
                  cvtpk(accB[td][2] * invB, accB[td][3] * invB) };
    *reinterpret_cast<uint2*>(opB + td * 16 + lg * 4) = wvB;
  }
}

extern "C" void kernel_launch(void* const* d_in, const int* in_sizes, int n_in,
                              void* d_out, int out_size, void* d_ws, size_t ws_size,
                              hipStream_t stream) {
  const float* x  = (const float*)d_in[0];
  const float* Wq = (const float*)d_in[1];
  const float* bq = (const float*)d_in[2];
  const float* Wk = (const float*)d_in[3];
  const float* bk = (const float*)d_in[4];
  const float* Wv = (const float*)d_in[5];
  const float* bv = (const float*)d_in[6];
  const float* Wo = (const float*)d_in[7];
  const float* bo = (const float*)d_in[8];
  const int*   pm = (const int*)d_in[9];

  char* ws = (char*)d_ws;
  const size_t MB = 1ull << 20;
  short* xb   = (short*)(ws + 0 * MB);
  short* q    = (short*)(ws + 16 * MB);
  short* kf   = (short*)(ws + 32 * MB);   // K' fragment-ready
  short* vf   = (short*)(ws + 48 * MB);   // V' fragment-ready
  short* ob   = (short*)(ws + 64 * MB);
  short* wqkv = (short*)(ws + 80 * MB);   // packed [3072][1024] bf16 (6 MB)
  short* wot  = (short*)(ws + 86 * MB);
  float* fbias = (float*)(ws + 88 * MB);

  k_cast<<<dim3(MTOT * DM / 8 / 256), dim3(256), 0, stream>>>(x, xb, MTOT * DM);
  k_maskbias<<<dim3(MTOT / 256), dim3(256), 0, stream>>>(pm, fbias, MTOT);
  k_transpose4<<<dim3(32, 32, 4), dim3(32, 8), 0, stream>>>(Wq, Wk, Wv, Wo, wqkv, wot);
  // fused QKV projection (Q pre-scaled by log2e/8 for log2-domain softmax)
  k_gemm_qkv<<<dim3(64, 24), dim3(256), 0, stream>>>(xb, wqkv, bq, bk, bv,
                                                     q, kf, vf, 0.125f * 1.44269504f);
  k_attn<<<dim3(SEQ / 32 * NB * NH), dim3(64), 0, stream>>>(q, kf, vf, fbias, ob);
  k_gemm_out<<<dim3(64, 8), dim3(256), 0, stream>>>(ob, wot, bo, (float*)d_out);
}